// Round 16
// baseline (218.838 us; speedup 1.0000x reference)
//
#include <hip/hip_runtime.h>
#include <hip/hip_fp16.h>

constexpr int N    = 100000;
constexpr int E    = 1000000;
constexpr int FIN  = 64;
constexpr int HID  = 128;
constexpr int NCLS = 32;
constexpr int G    = 1024;
constexpr float EPS = 1e-5f;

constexpr int NTILE = (N + 127) / 128;  // 782 row tiles

// ---- binned CSR build ----
constexpr int NBUCK = 196;     // dst >> 9, nodes/bucket = 512
constexpr int NPB   = 512;
constexpr int EPB   = 2048;    // edges per k_bin block (many blocks => TLP)
constexpr int CAP   = 6144;    // bucket capacity (mean 5102, sigma ~71)
constexpr int BIN_GRID = (E + EPB - 1) / EPB;  // 489

typedef _Float16 half2v __attribute__((ext_vector_type(2)));

__device__ inline float fdot2f(__half2 a, __half2 b, float c) {
#if __has_builtin(__builtin_amdgcn_fdot2)
  return __builtin_amdgcn_fdot2(*(half2v*)&a, *(half2v*)&b, c, false);
#else
  float2 fa = __half22float2(a), fb = __half22float2(b);
  return c + fa.x * fb.x + fa.y * fb.y;
#endif
}

// multi-split edges into buckets by dst>>9; packed u32 (dlocal<<17 | src)
__global__ __launch_bounds__(256) void k_bin(const int* __restrict__ src,
                                             const int* __restrict__ dst,
                                             int* __restrict__ bucketCursor,
                                             unsigned* __restrict__ bucketBuf) {
  __shared__ int bcnt[NBUCK];
  __shared__ int incl[256];    // inclusive scan (kept for flush search)
  __shared__ int bdelta[NBUCK];
  __shared__ int lcur[NBUCK];
  __shared__ unsigned staged[EPB];  // 8 KB
  int tid = threadIdx.x;
  int e0 = blockIdx.x * EPB;
  int cnt = E - e0 < EPB ? E - e0 : EPB;
  for (int i = tid; i < NBUCK; i += 256) bcnt[i] = 0;
  __syncthreads();
  for (int i = tid; i < cnt; i += 256) {
    atomicAdd(&bcnt[dst[e0 + i] >> 9], 1);
  }
  __syncthreads();
  incl[tid] = (tid < NBUCK) ? bcnt[tid] : 0;
  __syncthreads();
  for (int off = 1; off < 256; off <<= 1) {
    int t = (tid >= off) ? incl[tid - off] : 0;
    __syncthreads();
    incl[tid] += t;
    __syncthreads();
  }
  if (tid < NBUCK) {
    int excl = incl[tid] - bcnt[tid];
    int base = bcnt[tid] ? atomicAdd(&bucketCursor[tid], bcnt[tid]) : 0;
    bdelta[tid] = base - excl;
    lcur[tid]   = excl;
  }
  __syncthreads();
  for (int i = tid; i < cnt; i += 256) {
    int s = src[e0 + i], d = dst[e0 + i];
    int pos = atomicAdd(&lcur[d >> 9], 1);
    staged[pos] = ((unsigned)(d & 511) << 17) | (unsigned)s;
  }
  __syncthreads();
  for (int i = tid; i < cnt; i += 256) {
    unsigned p = staged[i];
    int lo = 0, hi = NBUCK - 1;  // smallest b with incl[b] > i
    while (lo < hi) { int m = (lo + hi) >> 1; if (incl[m] > i) hi = m; else lo = m + 1; }
    bucketBuf[(long long)lo * CAP + bdelta[lo] + i] = p;
  }
}

// one block per bucket (512 thr): LDS count -> offsets+dinv, LDS-cursor scatter,
// then fused y2 = fp16(x*dinv) for this bucket's 512 nodes (coalesced slab).
__global__ __launch_bounds__(512) void k_build(const int* __restrict__ bucketLen,
                                               const unsigned* __restrict__ bucketBuf,
                                               int* __restrict__ offsets,
                                               float* __restrict__ dinv,
                                               int* __restrict__ srclist,
                                               const float4* __restrict__ x4,
                                               float2* __restrict__ y2) {
  __shared__ int cnt[NPB];
  __shared__ int part[512];
  __shared__ int pre[256];
  __shared__ float sdinv[NPB];
  __shared__ int sh_bbase;
  int b = blockIdx.x, tid = threadIdx.x;
  int n0 = b << 9;
  int nn = (N - n0 < NPB) ? (N - n0) : NPB;
  int len = bucketLen[b];
  cnt[tid] = 0;
  if (tid < 256) pre[tid] = (tid < NBUCK) ? bucketLen[tid] : 0;
  __syncthreads();
  for (int off = 1; off < 256; off <<= 1) {
    int t = 0;
    if (tid < 256 && tid >= off) t = pre[tid - off];
    __syncthreads();
    if (tid < 256) pre[tid] += t;
    __syncthreads();
  }
  if (tid == b) sh_bbase = pre[b] - len;
  __syncthreads();
  const unsigned* buf = bucketBuf + (long long)b * CAP;
  for (int i = tid; i < len; i += 512)
    atomicAdd(&cnt[buf[i] >> 17], 1);
  __syncthreads();
  int v = cnt[tid];
  part[tid] = v;
  __syncthreads();
  for (int off = 1; off < 512; off <<= 1) {
    int t = (tid >= off) ? part[tid - off] : 0;
    __syncthreads();
    part[tid] += t;
    __syncthreads();
  }
  int o = sh_bbase + part[tid] - v;
  float dv = rsqrtf((float)v + 1.0f);
  sdinv[tid] = dv;
  __syncthreads();
  cnt[tid] = o;  // cursor
  if (tid < nn) {
    offsets[n0 + tid] = o;
    dinv[n0 + tid] = dv;
  }
  if (b == NBUCK - 1 && tid == 511) offsets[N] = sh_bbase + part[511];  // == E
  __syncthreads();
  for (int i = tid; i < len; i += 512) {
    unsigned p = buf[i];
    int pos = atomicAdd(&cnt[p >> 17], 1);
    srclist[pos] = (int)(p & 0x1FFFFu);
  }
  // fused scale: y2 rows for this bucket's nodes (coalesced 128 KB slab)
  const float4* xr = x4 + (long long)n0 * 16;
  float2* yr = y2 + (long long)n0 * 16;
  int tot = nn * 16;
  for (int i = tid; i < tot; i += 512) {
    float c = sdinv[i >> 4];
    float4 val = xr[i];
    union { float2 f; __half2 h[2]; } u;
    u.h[0] = __float22half2_rn(make_float2(val.x * c, val.y * c));
    u.h[1] = __float22half2_rn(make_float2(val.z * c, val.w * c));
    yr[i] = u.f;
  }
}

// W[64][128] f32 -> w2g[kp][col] half2 pairs along k; also zeroes accumulators
__global__ void k_wprep(const float* __restrict__ W, __half2* __restrict__ w2g,
                        int* __restrict__ bucketCursor, float* __restrict__ sums) {
  int idx = blockIdx.x * blockDim.x + threadIdx.x;  // 4096
  if (blockIdx.x == 0) bucketCursor[threadIdx.x] = 0;  // 256 >= NBUCK
  if (blockIdx.x == 1 && threadIdx.x < 64) {
    float* p = sums + threadIdx.x;  // 256 BN1 + 64 BN2 accumulators
    p[0] = 0.f; p[64] = 0.f; p[128] = 0.f; p[192] = 0.f; p[256] = 0.f;
  }
  if (idx >= 32 * 128) return;
  int kp = idx >> 7, col = idx & 127;
  w2g[idx] = __floats2half2_rn(W[(2 * kp) * 128 + col], W[(2 * kp + 1) * 128 + col]);
}

// 16 lanes/node, 8-edge unroll: agg[d] = fp16( dinv[d]*( y[d] + sum_s y[s] ) )
__global__ __launch_bounds__(256) void k_gather(const int* __restrict__ offsets,
                                                const int* __restrict__ srclist,
                                                const float* __restrict__ dinv,
                                                const float2* __restrict__ y2,
                                                float2* __restrict__ aggh) {
  int node = blockIdx.x * 16 + (threadIdx.x >> 4);
  int lane = threadIdx.x & 15;
  if (node >= N) return;
  int start = offsets[node], end = offsets[node + 1];
  float cd = dinv[node];

  union { float2 f; __half2 h[2]; } u;
  float4 a[4];
  u.f = y2[(long long)node * 16 + lane];
  {
    float2 p = __half22float2(u.h[0]), q = __half22float2(u.h[1]);
    a[0] = make_float4(p.x, p.y, q.x, q.y);
  }
  a[1] = make_float4(0.f, 0.f, 0.f, 0.f);
  a[2] = a[1]; a[3] = a[1];

  int i = start;
  for (; i + 7 < end; i += 8) {
    int sdx[8];
#pragma unroll
    for (int k = 0; k < 8; ++k) sdx[k] = srclist[i + k];
    float2 vv[8];
#pragma unroll
    for (int k = 0; k < 8; ++k) vv[k] = y2[(long long)sdx[k] * 16 + lane];
#pragma unroll
    for (int k = 0; k < 8; ++k) {
      union { float2 f; __half2 h[2]; } w;
      w.f = vv[k];
      float2 p = __half22float2(w.h[0]), q = __half22float2(w.h[1]);
      a[k & 3].x += p.x; a[k & 3].y += p.y; a[k & 3].z += q.x; a[k & 3].w += q.y;
    }
  }
  for (; i < end; ++i) {
    int s = srclist[i];
    u.f = y2[(long long)s * 16 + lane];
    float2 p = __half22float2(u.h[0]), q = __half22float2(u.h[1]);
    a[0].x += p.x; a[0].y += p.y; a[0].z += q.x; a[0].w += q.y;
  }
  float4 acc;
  acc.x = ((a[0].x + a[1].x) + (a[2].x + a[3].x)) * cd;
  acc.y = ((a[0].y + a[1].y) + (a[2].y + a[3].y)) * cd;
  acc.z = ((a[0].z + a[1].z) + (a[2].z + a[3].z)) * cd;
  acc.w = ((a[0].w + a[1].w) + (a[2].w + a[3].w)) * cd;
  union { float2 f; __half2 h[2]; } o;
  o.h[0] = __floats2half2_rn(acc.x, acc.y);
  o.h[1] = __floats2half2_rn(acc.z, acc.w);
  aggh[(long long)node * 16 + lane] = o.f;
}

// h2[N,128](fp16) = aggh[N,64](fp16) @ W(fp16 pairs) + b, fused BN1 stats (f32).
__global__ __launch_bounds__(256) void k_gemm2h(const __half2* __restrict__ aggh2,
                                                const __half2* __restrict__ w2g,
                                                const float* __restrict__ b,
                                                __half2* __restrict__ h2,
                                                float* __restrict__ sums) {
  __shared__ __half2 Wl[32 * 128];    // 16 KB
  __shared__ __half2 rowT[32 * 128];  // 16 KB
  int tid  = threadIdx.x;
  int row0 = blockIdx.x * 128;
  {
    const float4* srcv = (const float4*)w2g;
    float4* dstv = (float4*)Wl;
    for (int i = tid; i < 1024; i += 256) dstv[i] = srcv[i];
  }
  {
    int half = tid >> 7;
    int r = tid & 127;
    int grow = row0 + r;
#pragma unroll
    for (int c = 0; c < 4; ++c) {
      int kp0 = half * 16 + c * 4;
      float4 v = make_float4(0.f, 0.f, 0.f, 0.f);
      if (grow < N) v = *(const float4*)&aggh2[(long long)grow * 32 + kp0];
      __half2* pv = (__half2*)&v;
      rowT[(kp0 + 0) * 128 + r] = pv[0];
      rowT[(kp0 + 1) * 128 + r] = pv[1];
      rowT[(kp0 + 2) * 128 + r] = pv[2];
      rowT[(kp0 + 3) * 128 + r] = pv[3];
    }
  }
  __syncthreads();

  int rt = tid >> 4, ct = tid & 15;
  float acc[8][8];
#pragma unroll
  for (int m = 0; m < 8; ++m)
#pragma unroll
    for (int j = 0; j < 8; ++j) acc[m][j] = 0.f;

#pragma unroll 2
  for (int kp = 0; kp < 32; ++kp) {
    float4 wv0 = *(const float4*)&Wl[kp * 128 + ct * 8];
    float4 wv1 = *(const float4*)&Wl[kp * 128 + ct * 8 + 4];
    float4 rv0 = *(const float4*)&rowT[kp * 128 + rt * 8];
    float4 rv1 = *(const float4*)&rowT[kp * 128 + rt * 8 + 4];
    __half2 wv[8], rv[8];
    *(float4*)&wv[0] = wv0; *(float4*)&wv[4] = wv1;
    *(float4*)&rv[0] = rv0; *(float4*)&rv[4] = rv1;
#pragma unroll
    for (int m = 0; m < 8; ++m)
#pragma unroll
      for (int j = 0; j < 8; ++j) acc[m][j] = fdot2f(rv[m], wv[j], acc[m][j]);
  }

  int cbase = ct * 8;
  float4 b0 = *(const float4*)&b[cbase];
  float4 b1 = *(const float4*)&b[cbase + 4];
  float bias[8] = {b0.x, b0.y, b0.z, b0.w, b1.x, b1.y, b1.z, b1.w};
  float s[8], s2[8];
#pragma unroll
  for (int j = 0; j < 8; ++j) { s[j] = 0.f; s2[j] = 0.f; }
#pragma unroll
  for (int m = 0; m < 8; ++m) {
    int grow = row0 + rt * 8 + m;
    if (grow < N) {
      float hv[8];
#pragma unroll
      for (int j = 0; j < 8; ++j) {
        hv[j] = acc[m][j] + bias[j];
        s[j] += hv[j];
        s2[j] += hv[j] * hv[j];
      }
      union { float4 f; __half2 h[4]; } o;
      o.h[0] = __floats2half2_rn(hv[0], hv[1]);
      o.h[1] = __floats2half2_rn(hv[2], hv[3]);
      o.h[2] = __floats2half2_rn(hv[4], hv[5]);
      o.h[3] = __floats2half2_rn(hv[6], hv[7]);
      *(float4*)&h2[(long long)grow * 64 + ct * 4] = o.f;
    }
  }
  __syncthreads();
  float* red = (float*)Wl;
#pragma unroll
  for (int j = 0; j < 8; ++j) {
    red[rt * 256 + cbase + j]       = s[j];
    red[rt * 256 + 128 + cbase + j] = s2[j];
  }
  __syncthreads();
  float tot = 0.f;
#pragma unroll 4
  for (int r = 0; r < 16; ++r) tot += red[r * 256 + tid];
  atomicAdd(&sums[tid], tot);
}

// one block per graph: BN1 finalize (from sums) + ReLU + mean pool
__global__ __launch_bounds__(256) void k_pool(const __half2* __restrict__ h2,
                                              const float* __restrict__ sums,
                                              const float* __restrict__ w1,
                                              const float* __restrict__ b1,
                                              const int* __restrict__ batch,
                                              float* __restrict__ pooled) {
  __shared__ float sss[256];
  int tid = threadIdx.x;
  if (tid < 128) {
    float mu  = sums[tid] * (1.0f / N);
    float var = sums[tid + 128] * (1.0f / N) - mu * mu;
    float rs  = rsqrtf(var + EPS);
    float sc  = rs * w1[tid];
    sss[tid]       = sc;
    sss[tid + 128] = b1[tid] - mu * sc;
  }
  int g = blockIdx.x;
  int lo = 0, hi = N;
  while (lo < hi) { int m = (lo + hi) >> 1; if (batch[m] < g) lo = m + 1; else hi = m; }
  int lo2 = lo, hi2 = N;
  while (lo2 < hi2) { int m = (lo2 + hi2) >> 1; if (batch[m] < g + 1) lo2 = m + 1; else hi2 = m; }
  int start = lo, end = lo2;
  __syncthreads();
  int cp = tid & 63, rp = tid >> 6;
  float sc0 = sss[2 * cp], sc1 = sss[2 * cp + 1];
  float sh0 = sss[2 * cp + 128], sh1 = sss[2 * cp + 129];
  float s0 = 0.f, s1 = 0.f;
  for (int r = start + rp; r < end; r += 4) {
    float2 f = __half22float2(h2[(long long)r * 64 + cp]);
    s0 += fmaxf(f.x * sc0 + sh0, 0.f);
    s1 += fmaxf(f.y * sc1 + sh1, 0.f);
  }
  __shared__ float red0[256], red1[256];
  red0[tid] = s0; red1[tid] = s1;
  __syncthreads();
  if (tid < 64) {
#pragma unroll
    for (int q = 1; q < 4; ++q) { s0 += red0[tid + q * 64]; s1 += red1[tid + q * 64]; }
    float cnt = fmaxf((float)(end - start), 1.0f);
    float2 o = make_float2(s0 / cnt, s1 / cnt);
    *(float2*)&pooled[g * 128 + 2 * tid] = o;
  }
}

// head GEMV + per-column partial BN2 stats
__global__ __launch_bounds__(256) void k_head(const float* __restrict__ pooled,
                                              const float* __restrict__ W,
                                              const float* __restrict__ b,
                                              float* __restrict__ outpre,
                                              float* __restrict__ sums2) {
  int idx = blockIdx.x * 256 + threadIdx.x;  // 128 blocks cover G*NCLS
  int g = idx >> 5, c = idx & 31;
  float acc = b[c];
  const float* pr = pooled + g * 128;
#pragma unroll
  for (int k = 0; k < 128; ++k) acc += pr[k] * W[k * 32 + c];
  outpre[idx] = acc;
  __shared__ float red[256], red2[256];
  int tid = threadIdx.x;
  red[tid] = acc; red2[tid] = acc * acc;
  __syncthreads();
  for (int off = 128; off >= 32; off >>= 1) {
    if (tid < off) { red[tid] += red[tid + off]; red2[tid] += red2[tid + off]; }
    __syncthreads();
  }
  if (tid < 32) {
    atomicAdd(&sums2[tid], red[tid]);
    atomicAdd(&sums2[tid + 32], red2[tid]);
  }
}

// BN2 finalize (from sums2) + apply
__global__ __launch_bounds__(256) void k_bn2apply(const float* __restrict__ outpre,
                                                  const float* __restrict__ sums2,
                                                  const float* __restrict__ w2,
                                                  const float* __restrict__ b2,
                                                  float* __restrict__ out) {
  __shared__ float s2l[64];
  int tid = threadIdx.x;
  if (tid < 32) {
    float mu  = sums2[tid] * (1.0f / G);
    float var = sums2[tid + 32] * (1.0f / G) - mu * mu;
    float rs  = rsqrtf(var + EPS);
    float sc  = rs * w2[tid];
    s2l[tid]      = sc;
    s2l[tid + 32] = b2[tid] - mu * sc;
  }
  __syncthreads();
  int idx = blockIdx.x * 256 + tid;  // 128 blocks
  int c = idx & 31;
  out[idx] = outpre[idx] * s2l[c] + s2l[c + 32];
}

extern "C" void kernel_launch(void* const* d_in, const int* in_sizes, int n_in,
                              void* d_out, int out_size, void* d_ws, size_t ws_size,
                              hipStream_t stream) {
  const float* x   = (const float*)d_in[0];
  const int* ei    = (const int*)d_in[1];
  const int* batch = (const int*)d_in[2];
  const float* Wg  = (const float*)d_in[3];
  const float* bg  = (const float*)d_in[4];
  const float* w1  = (const float*)d_in[5];
  const float* b1  = (const float*)d_in[6];
  const float* Wo  = (const float*)d_in[7];
  const float* bo  = (const float*)d_in[8];
  const float* w2  = (const float*)d_in[9];
  const float* b2  = (const float*)d_in[10];

  float* ws     = (float*)d_ws;
  float* dinv   = ws;                        // 100352
  float* y2f    = dinv + 100352;             // N*16 float2 = 3.2M floats
  float* aggh_f = y2f + 3200000;             // N*64 halfs (pad 1600512 floats)
  float* h2f    = aggh_f + 1600512;          // N*128 halfs = 6.4M floats
  float* sums   = h2f + 6400000;             // 256 BN1 accum
  float* sums2  = sums + 256;                // 64 BN2 accum
  float* pooled = sums2 + 64;                // G*128
  float* outpre = pooled + G * 128;          // G*32
  int* offsets  = (int*)(outpre + G * 32);   // 100416
  int* srclist  = offsets + 100416;          // E
  int* bucketCursor = srclist + E;           // 256
  __half2* w2g  = (__half2*)(bucketCursor + 256);         // 4096
  unsigned* bucketBuf = (unsigned*)((float*)w2g + 4096);  // 196*6144 u32

  const int* src = ei;
  const int* dst = ei + E;

  k_wprep<<<16, 256, 0, stream>>>(Wg, w2g, bucketCursor, sums);
  k_bin<<<BIN_GRID, 256, 0, stream>>>(src, dst, bucketCursor, bucketBuf);
  k_build<<<NBUCK, 512, 0, stream>>>(bucketCursor, bucketBuf, offsets, dinv, srclist,
                                     (const float4*)x, (float2*)y2f);
  k_gather<<<(N + 15) / 16, 256, 0, stream>>>(offsets, srclist, dinv, (const float2*)y2f,
                                              (float2*)aggh_f);
  k_gemm2h<<<NTILE, 256, 0, stream>>>((const __half2*)aggh_f, w2g, bg,
                                      (__half2*)h2f, sums);
  k_pool<<<G, 256, 0, stream>>>((const __half2*)h2f, sums, w1, b1, batch, pooled);
  k_head<<<128, 256, 0, stream>>>(pooled, Wo, bo, outpre, sums2);
  k_bn2apply<<<128, 256, 0, stream>>>(outpre, sums2, w2, b2, (float*)d_out);
}

// Round 17
// 205.985 us; speedup vs baseline: 1.0624x; 1.0624x over previous
//
#include <hip/hip_runtime.h>
#include <hip/hip_fp16.h>

constexpr int N    = 100000;
constexpr int E    = 1000000;
constexpr int FIN  = 64;
constexpr int HID  = 128;
constexpr int NCLS = 32;
constexpr int G    = 1024;
constexpr float EPS = 1e-5f;

constexpr int NTILE = (N + 127) / 128;  // 782 row tiles

// ---- binned CSR build ----
constexpr int NBUCK = 196;     // dst >> 9, nodes/bucket = 512
constexpr int NPB   = 512;
constexpr int EPB   = 2048;    // edges per k_bin block (many blocks => TLP)
constexpr int CAP   = 6144;    // bucket capacity (mean 5102, sigma ~71)
constexpr int BIN_GRID = (E + EPB - 1) / EPB;  // 489

typedef _Float16 half2v __attribute__((ext_vector_type(2)));

__device__ inline float fdot2f(__half2 a, __half2 b, float c) {
#if __has_builtin(__builtin_amdgcn_fdot2)
  return __builtin_amdgcn_fdot2(*(half2v*)&a, *(half2v*)&b, c, false);
#else
  float2 fa = __half22float2(a), fb = __half22float2(b);
  return c + fa.x * fb.x + fa.y * fb.y;
#endif
}

// multi-split edges into buckets by dst>>9; packed u32 (dlocal<<17 | src)
__global__ __launch_bounds__(256) void k_bin(const int* __restrict__ src,
                                             const int* __restrict__ dst,
                                             int* __restrict__ bucketCursor,
                                             unsigned* __restrict__ bucketBuf) {
  __shared__ int bcnt[NBUCK];
  __shared__ int incl[256];
  __shared__ int bdelta[NBUCK];
  __shared__ int lcur[NBUCK];
  __shared__ unsigned staged[EPB];        // 8 KB
  __shared__ unsigned char sbuck[EPB];    // 2 KB: bucket id per staged slot
  int tid = threadIdx.x;
  int e0 = blockIdx.x * EPB;
  int cnt = E - e0 < EPB ? E - e0 : EPB;
  for (int i = tid; i < NBUCK; i += 256) bcnt[i] = 0;
  __syncthreads();
  for (int i = tid; i < cnt; i += 256) {
    atomicAdd(&bcnt[dst[e0 + i] >> 9], 1);
  }
  __syncthreads();
  incl[tid] = (tid < NBUCK) ? bcnt[tid] : 0;
  __syncthreads();
  for (int off = 1; off < 256; off <<= 1) {
    int t = (tid >= off) ? incl[tid - off] : 0;
    __syncthreads();
    incl[tid] += t;
    __syncthreads();
  }
  if (tid < NBUCK) {
    int excl = incl[tid] - bcnt[tid];
    int base = bcnt[tid] ? atomicAdd(&bucketCursor[tid], bcnt[tid]) : 0;
    bdelta[tid] = base - excl;
    lcur[tid]   = excl;
  }
  __syncthreads();
  for (int i = tid; i < cnt; i += 256) {
    int s = src[e0 + i], d = dst[e0 + i];
    int bno = d >> 9;
    int pos = atomicAdd(&lcur[bno], 1);
    staged[pos] = ((unsigned)(d & 511) << 17) | (unsigned)s;
    sbuck[pos]  = (unsigned char)bno;
  }
  __syncthreads();
  for (int i = tid; i < cnt; i += 256) {
    unsigned p = staged[i];
    int b = (int)sbuck[i];
    bucketBuf[(long long)b * CAP + bdelta[b] + i] = p;
  }
}

// one block per bucket (512 thr): LDS count -> offsets+dinv, LDS-cursor scatter,
// then fused y2 = fp16(x*dinv) for this bucket's 512 nodes (coalesced slab).
__global__ __launch_bounds__(512) void k_build(const int* __restrict__ bucketLen,
                                               const unsigned* __restrict__ bucketBuf,
                                               int* __restrict__ offsets,
                                               float* __restrict__ dinv,
                                               int* __restrict__ srclist,
                                               const float4* __restrict__ x4,
                                               float2* __restrict__ y2) {
  __shared__ int cnt[NPB];
  __shared__ int part[512];
  __shared__ int pre[256];
  __shared__ float sdinv[NPB];
  __shared__ int sh_bbase;
  int b = blockIdx.x, tid = threadIdx.x;
  int n0 = b << 9;
  int nn = (N - n0 < NPB) ? (N - n0) : NPB;
  int len = bucketLen[b];
  cnt[tid] = 0;
  if (tid < 256) pre[tid] = (tid < NBUCK) ? bucketLen[tid] : 0;
  __syncthreads();
  for (int off = 1; off < 256; off <<= 1) {
    int t = 0;
    if (tid < 256 && tid >= off) t = pre[tid - off];
    __syncthreads();
    if (tid < 256) pre[tid] += t;
    __syncthreads();
  }
  if (tid == b) sh_bbase = pre[b] - len;
  __syncthreads();
  const unsigned* buf = bucketBuf + (long long)b * CAP;
  for (int i = tid; i < len; i += 512)
    atomicAdd(&cnt[buf[i] >> 17], 1);
  __syncthreads();
  int v = cnt[tid];
  part[tid] = v;
  __syncthreads();
  for (int off = 1; off < 512; off <<= 1) {
    int t = (tid >= off) ? part[tid - off] : 0;
    __syncthreads();
    part[tid] += t;
    __syncthreads();
  }
  int o = sh_bbase + part[tid] - v;
  float dv = rsqrtf((float)v + 1.0f);
  sdinv[tid] = dv;
  __syncthreads();
  cnt[tid] = o;  // cursor
  if (tid < nn) {
    offsets[n0 + tid] = o;
    dinv[n0 + tid] = dv;
  }
  if (b == NBUCK - 1 && tid == 511) offsets[N] = sh_bbase + part[511];  // == E
  __syncthreads();
  for (int i = tid; i < len; i += 512) {
    unsigned p = buf[i];
    int pos = atomicAdd(&cnt[p >> 17], 1);
    srclist[pos] = (int)(p & 0x1FFFFu);
  }
  // fused scale: y2 rows for this bucket's nodes (coalesced 128 KB slab)
  const float4* xr = x4 + (long long)n0 * 16;
  float2* yr = y2 + (long long)n0 * 16;
  int tot = nn * 16;
  for (int i = tid; i < tot; i += 512) {
    float c = sdinv[i >> 4];
    float4 val = xr[i];
    union { float2 f; __half2 h[2]; } u;
    u.h[0] = __float22half2_rn(make_float2(val.x * c, val.y * c));
    u.h[1] = __float22half2_rn(make_float2(val.z * c, val.w * c));
    yr[i] = u.f;
  }
}

// W[64][128] f32 -> w2g[kp][col] half2 pairs along k; also zeroes accumulators
__global__ void k_wprep(const float* __restrict__ W, __half2* __restrict__ w2g,
                        int* __restrict__ bucketCursor, float* __restrict__ sums) {
  int idx = blockIdx.x * blockDim.x + threadIdx.x;  // 4096
  if (blockIdx.x == 0) bucketCursor[threadIdx.x] = 0;  // 256 >= NBUCK
  if (blockIdx.x == 1 && threadIdx.x < 64) {
    float* p = sums + threadIdx.x;  // 256 BN1 + 64 BN2 accumulators
    p[0] = 0.f; p[64] = 0.f; p[128] = 0.f; p[192] = 0.f; p[256] = 0.f;
  }
  if (idx >= 32 * 128) return;
  int kp = idx >> 7, col = idx & 127;
  w2g[idx] = __floats2half2_rn(W[(2 * kp) * 128 + col], W[(2 * kp + 1) * 128 + col]);
}

// 8 lanes/node, float4 rows, 4-edge unroll with 2 acc banks:
// agg[d] = fp16( dinv[d]*( y[d] + sum_s y[s] ) )
__global__ __launch_bounds__(256) void k_gather(const int* __restrict__ offsets,
                                                const int* __restrict__ srclist,
                                                const float* __restrict__ dinv,
                                                const float4* __restrict__ y4,
                                                float4* __restrict__ aggh4) {
  int node = blockIdx.x * 32 + (threadIdx.x >> 3);
  int lane = threadIdx.x & 7;
  if (node >= N) return;
  int start = offsets[node], end = offsets[node + 1];
  float cd = dinv[node];

  union U4 { float4 f; __half2 h[4]; };
  float A[8], B[8];
  {
    U4 u; u.f = y4[(long long)node * 8 + lane];
    float2 p0 = __half22float2(u.h[0]), p1 = __half22float2(u.h[1]);
    float2 p2 = __half22float2(u.h[2]), p3 = __half22float2(u.h[3]);
    A[0] = p0.x; A[1] = p0.y; A[2] = p1.x; A[3] = p1.y;
    A[4] = p2.x; A[5] = p2.y; A[6] = p3.x; A[7] = p3.y;
#pragma unroll
    for (int k = 0; k < 8; ++k) B[k] = 0.f;
  }

  int i = start;
  for (; i + 3 < end; i += 4) {
    int s0 = srclist[i], s1 = srclist[i + 1], s2 = srclist[i + 2], s3 = srclist[i + 3];
    U4 u0, u1, u2, u3;
    u0.f = y4[(long long)s0 * 8 + lane];
    u1.f = y4[(long long)s1 * 8 + lane];
    u2.f = y4[(long long)s2 * 8 + lane];
    u3.f = y4[(long long)s3 * 8 + lane];
    float2 p;
    p = __half22float2(u0.h[0]); A[0] += p.x; A[1] += p.y;
    p = __half22float2(u0.h[1]); A[2] += p.x; A[3] += p.y;
    p = __half22float2(u0.h[2]); A[4] += p.x; A[5] += p.y;
    p = __half22float2(u0.h[3]); A[6] += p.x; A[7] += p.y;
    p = __half22float2(u1.h[0]); B[0] += p.x; B[1] += p.y;
    p = __half22float2(u1.h[1]); B[2] += p.x; B[3] += p.y;
    p = __half22float2(u1.h[2]); B[4] += p.x; B[5] += p.y;
    p = __half22float2(u1.h[3]); B[6] += p.x; B[7] += p.y;
    p = __half22float2(u2.h[0]); A[0] += p.x; A[1] += p.y;
    p = __half22float2(u2.h[1]); A[2] += p.x; A[3] += p.y;
    p = __half22float2(u2.h[2]); A[4] += p.x; A[5] += p.y;
    p = __half22float2(u2.h[3]); A[6] += p.x; A[7] += p.y;
    p = __half22float2(u3.h[0]); B[0] += p.x; B[1] += p.y;
    p = __half22float2(u3.h[1]); B[2] += p.x; B[3] += p.y;
    p = __half22float2(u3.h[2]); B[4] += p.x; B[5] += p.y;
    p = __half22float2(u3.h[3]); B[6] += p.x; B[7] += p.y;
  }
  for (; i < end; ++i) {
    int s = srclist[i];
    U4 u; u.f = y4[(long long)s * 8 + lane];
    float2 p;
    p = __half22float2(u.h[0]); A[0] += p.x; A[1] += p.y;
    p = __half22float2(u.h[1]); A[2] += p.x; A[3] += p.y;
    p = __half22float2(u.h[2]); A[4] += p.x; A[5] += p.y;
    p = __half22float2(u.h[3]); A[6] += p.x; A[7] += p.y;
  }
  U4 o;
#pragma unroll
  for (int k = 0; k < 4; ++k)
    o.h[k] = __floats2half2_rn((A[2 * k] + B[2 * k]) * cd,
                               (A[2 * k + 1] + B[2 * k + 1]) * cd);
  aggh4[(long long)node * 8 + lane] = o.f;
}

// h2[N,128](fp16) = aggh[N,64](fp16) @ W(fp16 pairs) + b, fused BN1 stats (f32).
__global__ __launch_bounds__(256) void k_gemm2h(const __half2* __restrict__ aggh2,
                                                const __half2* __restrict__ w2g,
                                                const float* __restrict__ b,
                                                __half2* __restrict__ h2,
                                                float* __restrict__ sums) {
  __shared__ __half2 Wl[32 * 128];    // 16 KB
  __shared__ __half2 rowT[32 * 128];  // 16 KB
  int tid  = threadIdx.x;
  int row0 = blockIdx.x * 128;
  {
    const float4* srcv = (const float4*)w2g;
    float4* dstv = (float4*)Wl;
    for (int i = tid; i < 1024; i += 256) dstv[i] = srcv[i];
  }
  {
    int half = tid >> 7;
    int r = tid & 127;
    int grow = row0 + r;
#pragma unroll
    for (int c = 0; c < 4; ++c) {
      int kp0 = half * 16 + c * 4;
      float4 v = make_float4(0.f, 0.f, 0.f, 0.f);
      if (grow < N) v = *(const float4*)&aggh2[(long long)grow * 32 + kp0];
      __half2* pv = (__half2*)&v;
      rowT[(kp0 + 0) * 128 + r] = pv[0];
      rowT[(kp0 + 1) * 128 + r] = pv[1];
      rowT[(kp0 + 2) * 128 + r] = pv[2];
      rowT[(kp0 + 3) * 128 + r] = pv[3];
    }
  }
  __syncthreads();

  int rt = tid >> 4, ct = tid & 15;
  float acc[8][8];
#pragma unroll
  for (int m = 0; m < 8; ++m)
#pragma unroll
    for (int j = 0; j < 8; ++j) acc[m][j] = 0.f;

#pragma unroll 2
  for (int kp = 0; kp < 32; ++kp) {
    float4 wv0 = *(const float4*)&Wl[kp * 128 + ct * 8];
    float4 wv1 = *(const float4*)&Wl[kp * 128 + ct * 8 + 4];
    float4 rv0 = *(const float4*)&rowT[kp * 128 + rt * 8];
    float4 rv1 = *(const float4*)&rowT[kp * 128 + rt * 8 + 4];
    __half2 wv[8], rv[8];
    *(float4*)&wv[0] = wv0; *(float4*)&wv[4] = wv1;
    *(float4*)&rv[0] = rv0; *(float4*)&rv[4] = rv1;
#pragma unroll
    for (int m = 0; m < 8; ++m)
#pragma unroll
      for (int j = 0; j < 8; ++j) acc[m][j] = fdot2f(rv[m], wv[j], acc[m][j]);
  }

  int cbase = ct * 8;
  float4 b0 = *(const float4*)&b[cbase];
  float4 b1 = *(const float4*)&b[cbase + 4];
  float bias[8] = {b0.x, b0.y, b0.z, b0.w, b1.x, b1.y, b1.z, b1.w};
  float s[8], s2[8];
#pragma unroll
  for (int j = 0; j < 8; ++j) { s[j] = 0.f; s2[j] = 0.f; }
#pragma unroll
  for (int m = 0; m < 8; ++m) {
    int grow = row0 + rt * 8 + m;
    if (grow < N) {
      float hv[8];
#pragma unroll
      for (int j = 0; j < 8; ++j) {
        hv[j] = acc[m][j] + bias[j];
        s[j] += hv[j];
        s2[j] += hv[j] * hv[j];
      }
      union { float4 f; __half2 h[4]; } o;
      o.h[0] = __floats2half2_rn(hv[0], hv[1]);
      o.h[1] = __floats2half2_rn(hv[2], hv[3]);
      o.h[2] = __floats2half2_rn(hv[4], hv[5]);
      o.h[3] = __floats2half2_rn(hv[6], hv[7]);
      *(float4*)&h2[(long long)grow * 64 + ct * 4] = o.f;
    }
  }
  __syncthreads();
  float* red = (float*)Wl;
#pragma unroll
  for (int j = 0; j < 8; ++j) {
    red[rt * 256 + cbase + j]       = s[j];
    red[rt * 256 + 128 + cbase + j] = s2[j];
  }
  __syncthreads();
  float tot = 0.f;
#pragma unroll 4
  for (int r = 0; r < 16; ++r) tot += red[r * 256 + tid];
  atomicAdd(&sums[tid], tot);
}

// one block per graph: BN1 finalize (from sums) + ReLU + mean pool
__global__ __launch_bounds__(256) void k_pool(const __half2* __restrict__ h2,
                                              const float* __restrict__ sums,
                                              const float* __restrict__ w1,
                                              const float* __restrict__ b1,
                                              const int* __restrict__ batch,
                                              float* __restrict__ pooled) {
  __shared__ float sss[256];
  int tid = threadIdx.x;
  if (tid < 128) {
    float mu  = sums[tid] * (1.0f / N);
    float var = sums[tid + 128] * (1.0f / N) - mu * mu;
    float rs  = rsqrtf(var + EPS);
    float sc  = rs * w1[tid];
    sss[tid]       = sc;
    sss[tid + 128] = b1[tid] - mu * sc;
  }
  int g = blockIdx.x;
  int lo = 0, hi = N;
  while (lo < hi) { int m = (lo + hi) >> 1; if (batch[m] < g) lo = m + 1; else hi = m; }
  int lo2 = lo, hi2 = N;
  while (lo2 < hi2) { int m = (lo2 + hi2) >> 1; if (batch[m] < g + 1) lo2 = m + 1; else hi2 = m; }
  int start = lo, end = lo2;
  __syncthreads();
  int cp = tid & 63, rp = tid >> 6;
  float sc0 = sss[2 * cp], sc1 = sss[2 * cp + 1];
  float sh0 = sss[2 * cp + 128], sh1 = sss[2 * cp + 129];
  float s0 = 0.f, s1 = 0.f;
  for (int r = start + rp; r < end; r += 4) {
    float2 f = __half22float2(h2[(long long)r * 64 + cp]);
    s0 += fmaxf(f.x * sc0 + sh0, 0.f);
    s1 += fmaxf(f.y * sc1 + sh1, 0.f);
  }
  __shared__ float red0[256], red1[256];
  red0[tid] = s0; red1[tid] = s1;
  __syncthreads();
  if (tid < 64) {
#pragma unroll
    for (int q = 1; q < 4; ++q) { s0 += red0[tid + q * 64]; s1 += red1[tid + q * 64]; }
    float cnt = fmaxf((float)(end - start), 1.0f);
    float2 o = make_float2(s0 / cnt, s1 / cnt);
    *(float2*)&pooled[g * 128 + 2 * tid] = o;
  }
}

// head GEMV + per-column partial BN2 stats
__global__ __launch_bounds__(256) void k_head(const float* __restrict__ pooled,
                                              const float* __restrict__ W,
                                              const float* __restrict__ b,
                                              float* __restrict__ outpre,
                                              float* __restrict__ sums2) {
  int idx = blockIdx.x * 256 + threadIdx.x;  // 128 blocks cover G*NCLS
  int g = idx >> 5, c = idx & 31;
  float acc = b[c];
  const float* pr = pooled + g * 128;
#pragma unroll
  for (int k = 0; k < 128; ++k) acc += pr[k] * W[k * 32 + c];
  outpre[idx] = acc;
  __shared__ float red[256], red2[256];
  int tid = threadIdx.x;
  red[tid] = acc; red2[tid] = acc * acc;
  __syncthreads();
  for (int off = 128; off >= 32; off >>= 1) {
    if (tid < off) { red[tid] += red[tid + off]; red2[tid] += red2[tid + off]; }
    __syncthreads();
  }
  if (tid < 32) {
    atomicAdd(&sums2[tid], red[tid]);
    atomicAdd(&sums2[tid + 32], red2[tid]);
  }
}

// BN2 finalize (from sums2) + apply
__global__ __launch_bounds__(256) void k_bn2apply(const float* __restrict__ outpre,
                                                  const float* __restrict__ sums2,
                                                  const float* __restrict__ w2,
                                                  const float* __restrict__ b2,
                                                  float* __restrict__ out) {
  __shared__ float s2l[64];
  int tid = threadIdx.x;
  if (tid < 32) {
    float mu  = sums2[tid] * (1.0f / G);
    float var = sums2[tid + 32] * (1.0f / G) - mu * mu;
    float rs  = rsqrtf(var + EPS);
    float sc  = rs * w2[tid];
    s2l[tid]      = sc;
    s2l[tid + 32] = b2[tid] - mu * sc;
  }
  __syncthreads();
  int idx = blockIdx.x * 256 + tid;  // 128 blocks
  int c = idx & 31;
  out[idx] = outpre[idx] * s2l[c] + s2l[c + 32];
}

extern "C" void kernel_launch(void* const* d_in, const int* in_sizes, int n_in,
                              void* d_out, int out_size, void* d_ws, size_t ws_size,
                              hipStream_t stream) {
  const float* x   = (const float*)d_in[0];
  const int* ei    = (const int*)d_in[1];
  const int* batch = (const int*)d_in[2];
  const float* Wg  = (const float*)d_in[3];
  const float* bg  = (const float*)d_in[4];
  const float* w1  = (const float*)d_in[5];
  const float* b1  = (const float*)d_in[6];
  const float* Wo  = (const float*)d_in[7];
  const float* bo  = (const float*)d_in[8];
  const float* w2  = (const float*)d_in[9];
  const float* b2  = (const float*)d_in[10];

  float* ws     = (float*)d_ws;
  float* dinv   = ws;                        // 100352
  float* y2f    = dinv + 100352;             // N*16 float2 = 3.2M floats
  float* aggh_f = y2f + 3200000;             // N*64 halfs (pad 1600512 floats)
  float* h2f    = aggh_f + 1600512;          // N*128 halfs = 6.4M floats
  float* sums   = h2f + 6400000;             // 256 BN1 accum
  float* sums2  = sums + 256;                // 64 BN2 accum
  float* pooled = sums2 + 64;                // G*128
  float* outpre = pooled + G * 128;          // G*32
  int* offsets  = (int*)(outpre + G * 32);   // 100416
  int* srclist  = offsets + 100416;          // E
  int* bucketCursor = srclist + E;           // 256
  __half2* w2g  = (__half2*)(bucketCursor + 256);         // 4096
  unsigned* bucketBuf = (unsigned*)((float*)w2g + 4096);  // 196*6144 u32

  const int* src = ei;
  const int* dst = ei + E;

  k_wprep<<<16, 256, 0, stream>>>(Wg, w2g, bucketCursor, sums);
  k_bin<<<BIN_GRID, 256, 0, stream>>>(src, dst, bucketCursor, bucketBuf);
  k_build<<<NBUCK, 512, 0, stream>>>(bucketCursor, bucketBuf, offsets, dinv, srclist,
                                     (const float4*)x, (float2*)y2f);
  k_gather<<<(N + 31) / 32, 256, 0, stream>>>(offsets, srclist, dinv,
                                              (const float4*)y2f, (float4*)aggh_f);
  k_gemm2h<<<NTILE, 256, 0, stream>>>((const __half2*)aggh_f, w2g, bg,
                                      (__half2*)h2f, sums);
  k_pool<<<G, 256, 0, stream>>>((const __half2*)h2f, sums, w1, b1, batch, pooled);
  k_head<<<128, 256, 0, stream>>>(pooled, Wo, bo, outpre, sums2);
  k_bn2apply<<<128, 256, 0, stream>>>(outpre, sums2, w2, b2, (float*)d_out);
}